// Round 12
// baseline (93.137 us; speedup 1.0000x reference)
//
#include <hip/hip_runtime.h>

#define TT 32     // tags
#define LL 16     // max span length
#define BURN 16   // burn-in steps (validated r11: absmax 0.0 at BURN=16)
#define KCH 16    // chunk payload length (steps)

// ---------------------------------------------------------------------------
// Duo chunk-parallel scan: ONE WAVE PROCESSES TWO CHUNKS (half-wave each).
// Lane layout: tl = lane&31 (tag), h = lane>>5 (which chunk of the pair).
// Chunk ch = 2*bs + h covers payload [ch*16, (ch+1)*16); gstart =
// max(0, (ch-1)*16). bs==0 -> both halves exact-from-0 (chunk 0 contributes
// its absolute m at step 15 = the pre-rescale capture; chunk 1 contributes
// m(31)-m(15); telescoping exact). bs>0 -> both halves burn in 16 steps from
// an all-ones state (projective contraction, absmax 0.0 measured).
//
// Per lane: FULL 32-wide state. D[q] = sum_{p=0..31} Trx[t][p]*Hnorm_{s'(q)}[p]
// (MVM = 8x broadcast ds_read_b128 + 32 fma, all in-lane -> no cross-lane
// reduce on the chain). Emissions staged via register->LDS double-buffered
// ring, 4-step groups, float4 per lane (512B contiguous per half-plane).
// ---------------------------------------------------------------------------
__launch_bounds__(64, 1)
__global__ void semicrf_duo_kernel(const float* __restrict__ feats,
                                   const float* __restrict__ trans,
                                   const float* __restrict__ tbound,
                                   const float* __restrict__ w1p,
                                   const float* __restrict__ w2p,
                                   float* __restrict__ ws2,
                                   int S, int C, int swz) {
    __shared__ __align__(16) float ring0[16 * 256];  // 16 planes x 2 halves x 128
    __shared__ __align__(16) float ring1[16 * 256];
    __shared__ __align__(16) float ldsS[64];         // [h][t] current Sv
    int bs = (int)blockIdx.x;
    const int NB = C >> 1;
    if (swz) bs = (bs & 7) * (NB >> 3) + (bs >> 3);  // XCD-contiguous pairs
    const int lane = (int)threadIdx.x;
    const int tl = lane & 31;
    const int h = lane >> 5;
    const int ch = 2 * bs + h;
    const float w1 = w1p[0];
    const float w2 = w2p[0];
    const int Sm1 = S - 1;
    const bool exact = (bs == 0);                    // both halves gstart==0
    int s0 = exact ? 0 : (ch - 1) * 16;              // per-half window start

    // full Trx row for this lane's tag (32 regs)
    float trx[32];
#pragma unroll
    for (int i = 0; i < 32; ++i)
        trx[i] = __expf(w1 * trans[tl * TT + i]);
    float trxsum = 0.0f;
#pragma unroll
    for (int i = 0; i < 32; ++i) trxsum += trx[i];

    float D[16];
#pragma unroll
    for (int k = 0; k < 16; ++k) D[k] = exact ? 0.0f : trxsum;
    if (!exact) ldsS[lane] = 1.0f;                   // ones init (H_{-1}=1)

    float etb0 = __expf(w1 * tbound[tl]);
    float bem[16];
#pragma unroll
    for (int j = 0; j < 16; ++j) bem[j] = 0.0f;
    if (exact) {
#pragma unroll
        for (int j = 0; j < 16; ++j)                 // bemit[j] = feats[j][0][t]
            bem[j] = __expf(w2 * feats[(size_t)j * (size_t)S * 32u + (size_t)tl]);
    }

    float mref = 0.0f, Svk = 1.0f, inv = 1.0f;
    float4 gst[16];                                  // staged: next group

// issue 16 float4 loads (4 steps x 32 t per plane, this half's window)
#define LOADG(OFF)                                                            \
    {                                                                         \
        int gs_ = s0 + (OFF); if (gs_ > S - 4) gs_ = S - 4;                   \
        _Pragma("unroll")                                                     \
        for (int l = 0; l < 16; ++l)                                          \
            gst[l] = *(const float4*)(feats +                                 \
                        ((size_t)l * (size_t)Sm1 + (size_t)gs_) * 32 + tl * 4);\
    }

// write staged regs into ring buffer P, then issue loads at offset OFF
#define GROUPOPS(P, OFF)                                                      \
    {                                                                         \
        float* rw_ = (P) ? ring1 : ring0;                                     \
        _Pragma("unroll")                                                     \
        for (int l = 0; l < 16; ++l)                                          \
            *(float4*)&rw_[l * 256 + h * 128 + tl * 4] = gst[l];              \
        LOADG(OFF)                                                            \
    }

#define SCRF_STEP(J, IS_B0, IS_FIRST, SCALED)                                 \
    {                                                                         \
        const int j_ = (J);                                                   \
        const float* rb_ = ((j_ >> 2) & 1) ? ring1 : ring0;                   \
        /* 16 emissions (1/span-length) from the ring; bank = tl, 2-way ok */ \
        float ew_[16];                                                        \
        _Pragma("unroll")                                                     \
        for (int l = 0; l < 16; ++l)                                          \
            ew_[l] = __expf(w2 * rb_[l * 256 + h * 128 + (j_ & 3) * 32 + tl]);\
        /* full MVM from ldsS (broadcast reads) -> D[(j-1)&15] (chain head) */\
        float Dn_;                                                            \
        if (IS_FIRST) {                                                       \
            Dn_ = 0.0f;                                                       \
        } else {                                                              \
            const float4* lp_ = (const float4*)(ldsS + h * 32);               \
            float4 a0_ = lp_[0], a1_ = lp_[1], a2_ = lp_[2], a3_ = lp_[3];    \
            float4 a4_ = lp_[4], a5_ = lp_[5], a6_ = lp_[6], a7_ = lp_[7];    \
            float d0_ = fmaf(trx[0],  a0_.x, fmaf(trx[1],  a0_.y,             \
                        fmaf(trx[2],  a0_.z, trx[3]  * a0_.w)));              \
            float d1_ = fmaf(trx[4],  a1_.x, fmaf(trx[5],  a1_.y,             \
                        fmaf(trx[6],  a1_.z, trx[7]  * a1_.w)));              \
            float d2_ = fmaf(trx[8],  a2_.x, fmaf(trx[9],  a2_.y,             \
                        fmaf(trx[10], a2_.z, trx[11] * a2_.w)));              \
            float d3_ = fmaf(trx[12], a3_.x, fmaf(trx[13], a3_.y,             \
                        fmaf(trx[14], a3_.z, trx[15] * a3_.w)));              \
            float d4_ = fmaf(trx[16], a4_.x, fmaf(trx[17], a4_.y,             \
                        fmaf(trx[18], a4_.z, trx[19] * a4_.w)));              \
            float d5_ = fmaf(trx[20], a5_.x, fmaf(trx[21], a5_.y,             \
                        fmaf(trx[22], a5_.z, trx[23] * a5_.w)));              \
            float d6_ = fmaf(trx[24], a6_.x, fmaf(trx[25], a6_.y,             \
                        fmaf(trx[26], a6_.z, trx[27] * a6_.w)));              \
            float d7_ = fmaf(trx[28], a7_.x, fmaf(trx[29], a7_.y,             \
                        fmaf(trx[30], a7_.z, trx[31] * a7_.w)));              \
            float dh_ = ((d0_ + d1_) + (d2_ + d3_)) +                         \
                        ((d4_ + d5_) + (d6_ + d7_));                          \
            Dn_ = (SCALED) ? dh_ * inv : dh_;                                 \
            D[(j_ - 1) & 15] = Dn_;                                           \
        }                                                                     \
        /* partial over l=1..15 (off the chain); full-dot D -> S_t in-lane */ \
        float q0_ = D[(j_ - 2) & 15] * ew_[1];                                \
        float q1_ = D[(j_ - 3) & 15] * ew_[2];                                \
        float q2_ = D[(j_ - 4) & 15] * ew_[3];                                \
        float q3_ = D[(j_ - 5) & 15] * ew_[4];                                \
        q0_ = fmaf(D[(j_ - 6) & 15], ew_[5], q0_);                            \
        q1_ = fmaf(D[(j_ - 7) & 15], ew_[6], q1_);                            \
        q2_ = fmaf(D[(j_ - 8) & 15], ew_[7], q2_);                            \
        q3_ = fmaf(D[(j_ - 9) & 15], ew_[8], q3_);                            \
        q0_ = fmaf(D[(j_ - 10) & 15], ew_[9], q0_);                           \
        q1_ = fmaf(D[(j_ - 11) & 15], ew_[10], q1_);                          \
        q2_ = fmaf(D[(j_ - 12) & 15], ew_[11], q2_);                          \
        q3_ = fmaf(D[(j_ - 13) & 15], ew_[12], q3_);                          \
        q0_ = fmaf(D[(j_ - 14) & 15], ew_[13], q0_);                          \
        q1_ = fmaf(D[(j_ - 15) & 15], ew_[14], q1_);                          \
        q2_ = fmaf(D[(j_ - 16) & 15], ew_[15], q2_);                          \
        float p15_ = (q0_ + q1_) + (q2_ + q3_);                               \
        p15_ = (tl == 0) ? 0.0f : p15_;    /* O-tag: span len 1 only */       \
        float Sv_ = fmaf(Dn_, ew_[0], p15_);                                  \
        if (IS_B0) {                                                          \
            float bt_ = etb0 * bem[j_];                                       \
            if (j_ > 0) bt_ = (tl == 0) ? 0.0f : bt_;                         \
            Sv_ += bt_;                                                       \
        }                                                                     \
        ldsS[lane] = Sv_;                                                     \
        Svk = Sv_;                                                            \
    }

// one 16-step block = 4 groups; invariant on entry: ring0 = steps s0+0..3,
// gst = steps s0+4..7; exit: ring0 = next block's first group, gst = second.
#define BLOCK16(B0, FIRST, SCALED)                                            \
    SCRF_STEP(0, B0, FIRST, SCALED)                                           \
    SCRF_STEP(1, B0, false, false)                                            \
    SCRF_STEP(2, B0, false, false)                                            \
    SCRF_STEP(3, B0, false, false)                                            \
    GROUPOPS(1, 8)                                                            \
    SCRF_STEP(4, B0, false, false)                                            \
    SCRF_STEP(5, B0, false, false)                                            \
    SCRF_STEP(6, B0, false, false)                                            \
    SCRF_STEP(7, B0, false, false)                                            \
    GROUPOPS(0, 12)                                                           \
    SCRF_STEP(8, B0, false, false)                                            \
    SCRF_STEP(9, B0, false, false)                                            \
    SCRF_STEP(10, B0, false, false)                                           \
    SCRF_STEP(11, B0, false, false)                                           \
    GROUPOPS(1, 16)                                                           \
    SCRF_STEP(12, B0, false, false)                                           \
    SCRF_STEP(13, B0, false, false)                                           \
    SCRF_STEP(14, B0, false, false)                                           \
    SCRF_STEP(15, B0, false, false)                                           \
    GROUPOPS(0, 20)

    // ---- prologue: group 0 -> ring0, stage group 1 ----
    LOADG(0)
    {
        float* rw_ = ring0;
#pragma unroll
        for (int l = 0; l < 16; ++l)
            *(float4*)&rw_[l * 256 + h * 128 + tl * 4] = gst[l];
    }
    LOADG(4)

    // ---- block 0 (burn-in for bs>0; exact+boundary for bs==0) ----
    if (exact) {
        BLOCK16(true, true, false)
    } else {
        BLOCK16(false, false, false)
    }

    // ---- capture m at local step 15 (pre-rescale) ----
    float sv = Svk;
#pragma unroll
    for (int m = 1; m <= 16; m <<= 1) sv += __shfl_xor(sv, m);
    float m_pre = mref + __logf(sv);

    // ---- rescale: D /= max_t(Sv), recenter to e^-20 ----
    float mx = Svk;
#pragma unroll
    for (int m = 1; m <= 16; m <<= 1) mx = fmaxf(mx, __shfl_xor(mx, m));
    inv = 2.0611536e-09f / mx;          // e^-20 / mx
    mref += __logf(mx) + 20.0f;
#pragma unroll
    for (int k = 0; k < 16; ++k) D[k] *= inv;

    // ---- block 1 (payload for bs>0; chunk-1 payload for bs==0) ----
    s0 += 16;
    BLOCK16(false, false, true)
#undef BLOCK16
#undef SCRF_STEP
#undef GROUPOPS
#undef LOADG

    // ---- chunk outputs (per half) ----
    float se = Svk;
#pragma unroll
    for (int m = 1; m <= 16; m <<= 1) se += __shfl_xor(se, m);
    float m_end = mref + __logf(se);
    // chunk 0's payload ends at local step 15 -> its contribution is m_pre
    float contrib = (ch == 0) ? m_pre : (m_end - m_pre);
    if (tl == 0) ws2[ch] = contrib;
    if (ch == C - 1) {
        float etb1 = __expf(w1 * tbound[TT + tl]);
        float sc = Svk * etb1;
#pragma unroll
        for (int m = 1; m <= 16; m <<= 1) sc += __shfl_xor(sc, m);
        if (tl == 0) ws2[C] = __logf(sc) - __logf(se);
    }
}

// ---------------------------------------------------------------------------
// Ordered reduction of the C+1 chunk contributions.
// ---------------------------------------------------------------------------
__global__ void stitch_kernel(const float* __restrict__ ws2,
                              float* __restrict__ out, int n) {
    const int lane = (int)threadIdx.x;
    float v = 0.0f;
    for (int i = lane; i < n; i += 64) v += ws2[i];
#pragma unroll
    for (int m = 1; m <= 32; m <<= 1) v += __shfl_xor(v, m);
    if (lane == 0) out[0] = v;
}

// ---------------------------------------------------------------------------
// Fallback (S not a multiple of 32 / tiny ws): proven round-2 kernel.
// ---------------------------------------------------------------------------
__launch_bounds__(64, 1)
__global__ void semicrf_scan_fb_kernel(const float* __restrict__ src,
                                       const float* __restrict__ trans,
                                       const float* __restrict__ tbound,
                                       const float* __restrict__ w1p,
                                       const float* __restrict__ w2p,
                                       float* __restrict__ out, int S) {
    __shared__ float4 ldsS4[8];
    const int lane = threadIdx.x;
    const int t = lane & 31;
    const int h = lane >> 5;
    const float w1 = w1p[0];
    const float w2 = w2p[0];
    const unsigned toff = (unsigned)t * 4u;
    const unsigned planeB = (unsigned)S * 128u;
    const size_t planeE = (size_t)S * TT;

    float trx[16];
#pragma unroll
    for (int i = 0; i < 16; ++i)
        trx[i] = __expf(w1 * trans[t * TT + h * 16 + i]);

    float D[16];
#pragma unroll
    for (int k = 0; k < 16; ++k) D[k] = 0.0f;

    unsigned off[16];
#pragma unroll
    for (int k = 0; k < 16; ++k) {
        int l = (-1 - k) & 15;
        int c = 0 - l; if (c < 0) c = 0;
        off[k] = (unsigned)(l * S + c) * 128u + toff;
    }

    float ring[4][16];
#pragma unroll
    for (int st = 0; st < 4; ++st) {
#pragma unroll
        for (int k = 0; k < 16; ++k)
            ring[st][k] = *(const float*)((const char*)src + off[k]);
        const int qr = st & 15;
        unsigned c = (unsigned)((st + 1 <= S - 1) ? st + 1 : S - 1);
#pragma unroll
        for (int k = 0; k < 16; ++k)
            off[k] = (k == qr) ? (c * 128u + toff) : (off[k] + planeB);
    }

    float etb0 = __expf(w1 * tbound[t]);
    float bem[16];
#pragma unroll
    for (int j = 0; j < 16; ++j)
        bem[j] = __expf(w2 * src[(size_t)j * planeE + (size_t)t]);

    float mref = 0.0f;
    float Svk = 1.0f;

#define FB_STEP(J, S0V, IS_B0)                                                \
    {                                                                         \
        const int j_ = (J);                                                   \
        float ewv[16];                                                        \
        _Pragma("unroll")                                                     \
        for (int k = 0; k < 16; ++k)                                          \
            ewv[k] = __expf(w2 * ring[j_ & 3][k]);                            \
        float p0 = 0.f, p1 = 0.f, p2 = 0.f, p3 = 0.f;                         \
        _Pragma("unroll")                                                     \
        for (int k = 0; k < 16; k += 4) {                                     \
            p0 = fmaf(D[k + 0], ewv[k + 0], p0);                              \
            p1 = fmaf(D[k + 1], ewv[k + 1], p1);                              \
            p2 = fmaf(D[k + 2], ewv[k + 2], p2);                              \
            p3 = fmaf(D[k + 3], ewv[k + 3], p3);                              \
        }                                                                     \
        float part = (p0 + p1) + (p2 + p3);                                   \
        {                                                                     \
            const int kp = (j_ - 1) & 15;                                     \
            float alt = D[kp] * ewv[kp];                                      \
            part = (t == 0) ? alt : part;                                     \
        }                                                                     \
        _Pragma("unroll")                                                     \
        for (int k = 0; k < 16; ++k)                                          \
            ring[(j_ + 4) & 3][k] =                                           \
                *(const float*)((const char*)src + off[k]);                   \
        {                                                                     \
            const int qr = (j_ + 4) & 15;                                     \
            long T1 = (long)(S0V) + j_ + 4 + 1;                               \
            unsigned c_ = (unsigned)(T1 <= (long)(S - 1) ? T1 : (long)(S - 1)); \
            _Pragma("unroll")                                                 \
            for (int k = 0; k < 16; ++k)                                      \
                off[k] = (k == qr) ? (c_ * 128u + toff) : (off[k] + planeB);  \
        }                                                                     \
        float Sv = part + __shfl_xor(part, 32);                               \
        if (IS_B0) {                                                          \
            float bt = etb0 * bem[j_];                                        \
            if (j_ > 0) bt = (t == 0) ? 0.0f : bt;                            \
            Sv += bt;                                                         \
        }                                                                     \
        ((float*)ldsS4)[t] = Sv;                                              \
        __syncthreads();                                                      \
        float4 a0 = ldsS4[h * 4 + 0];                                         \
        float4 a1 = ldsS4[h * 4 + 1];                                         \
        float4 a2 = ldsS4[h * 4 + 2];                                         \
        float4 a3 = ldsS4[h * 4 + 3];                                         \
        float dn0 = fmaf(trx[0],  a0.x, fmaf(trx[1],  a0.y,                   \
                    fmaf(trx[2],  a0.z, trx[3]  * a0.w)));                    \
        float dn1 = fmaf(trx[4],  a1.x, fmaf(trx[5],  a1.y,                   \
                    fmaf(trx[6],  a1.z, trx[7]  * a1.w)));                    \
        float dn2 = fmaf(trx[8],  a2.x, fmaf(trx[9],  a2.y,                   \
                    fmaf(trx[10], a2.z, trx[11] * a2.w)));                    \
        float dn3 = fmaf(trx[12], a3.x, fmaf(trx[13], a3.y,                   \
                    fmaf(trx[14], a3.z, trx[15] * a3.w)));                    \
        D[j_] = (dn0 + dn1) + (dn2 + dn3);                                    \
        Svk = Sv;                                                             \
    }

#pragma unroll
    for (int j = 0; j < 16; ++j) {
        FB_STEP(j, 0L, true)
    }
    const int nblocks = S / 16;
    long s0 = 16;
    for (int b = 1; b < nblocks; ++b) {
        float mx = Svk;
#pragma unroll
        for (int m = 1; m <= 16; m <<= 1)
            mx = fmaxf(mx, __shfl_xor(mx, m));
        float invv = 2.0611536e-09f / mx;
        mref += __logf(mx) + 20.0f;
#pragma unroll
        for (int k = 0; k < 16; ++k) D[k] *= invv;
#pragma unroll
        for (int j = 0; j < 16; ++j) {
            FB_STEP(j, s0, false)
        }
        s0 += 16;
    }
#undef FB_STEP

    float etb1 = __expf(w1 * tbound[TT + t]);
    float val = Svk * etb1;
#pragma unroll
    for (int m = 1; m <= 16; m <<= 1) val += __shfl_xor(val, m);
    if (lane == 0) out[0] = mref + __logf(val);
}

// ---------------------------------------------------------------------------
extern "C" void kernel_launch(void* const* d_in, const int* in_sizes, int n_in,
                              void* d_out, int out_size, void* d_ws, size_t ws_size,
                              hipStream_t stream) {
    const float* feats = (const float*)d_in[0];   // [L=16, S, T=32]
    const float* trans = (const float*)d_in[1];   // [T, T]
    const float* tb    = (const float*)d_in[2];   // [2, T]
    const float* w1    = (const float*)d_in[3];
    const float* w2    = (const float*)d_in[4];
    float* out = (float*)d_out;

    const int n = in_sizes[0];            // L*S*T
    const int S = n / (LL * TT);

    // K=16 chunks, 2 per wave: need S % 32 == 0 so C is even.
    int C = 0;
    if ((S & 31) == 0 && S >= 64) C = S >> 4;
    const int NB = C >> 1;
    const int swz = (NB > 0 && (NB & 7) == 0) ? 1 : 0;

    const size_t need = (size_t)(C + 2) * sizeof(float);
    if (C > 1 && ws_size >= need) {
        float* ws2 = (float*)d_ws;
        semicrf_duo_kernel<<<NB, 64, 0, stream>>>(feats, trans, tb, w1, w2,
                                                  ws2, S, C, swz);
        stitch_kernel<<<1, 64, 0, stream>>>(ws2, out, C + 1);
    } else {
        semicrf_scan_fb_kernel<<<1, 64, 0, stream>>>(feats, trans, tb, w1, w2, out, S);
    }
}

// Round 13
// 48.544 us; speedup vs baseline: 1.9186x; 1.9186x over previous
//
#include <hip/hip_runtime.h>

#define TT 32     // tags
#define LL 16     // max span length
#define BURN 16   // burn-in steps (validated r11: absmax 0.0)
#define KCH 16    // chunk payload length (steps)

// lane<->lane^32 sum via permlane32_swap (VALU) with shfl fallback
__device__ __forceinline__ float swap_sum(float x) {
#if __has_builtin(__builtin_amdgcn_permlane32_swap)
    typedef unsigned int u2 __attribute__((ext_vector_type(2)));
    u2 r = __builtin_amdgcn_permlane32_swap(__float_as_uint(x), __float_as_uint(x),
                                            false, false);
    return __uint_as_float(r.x) + __uint_as_float(r.y);
#else
    return x + __shfl_xor(x, 32);
#endif
}

// ---------------------------------------------------------------------------
// Duo-chain chunk-parallel scan: one wave runs TWO INDEPENDENT full-wave
// chains (chunks 2bs and 2bs+1), instruction-interleaved. Each chain uses the
// proven r10 step layout (t = lane&31, h = lane>>5 splits the p-sum; D[q] =
// half-dot; MVM = 4x broadcast ds_read_b128 + 16 fma; S_t via swap_sum).
// Chain A's ldsS write->read latency hides under chain B's instructions and
// vice versa. trx/bem/etb0 prologue is shared. Adjacent chunks' windows
// overlap 50% -> L2-co-resident within the block.
// Chunk ch covers payload [ch*16,(ch+1)*16); window starts at (ch-1)*16
// (clamped to 0). bs==0: both chains exact-from-0 (identical 32-step runs;
// chunk0 contributes m(15), chunk1 contributes m(31)-m(15)). bs>0: block0 =
// burn-in from all-ones, block1 = payload; contribution m_end - m_pre.
// ---------------------------------------------------------------------------
__launch_bounds__(64, 1)
__global__ void semicrf_duo2_kernel(const float* __restrict__ feats,
                                    const float* __restrict__ trans,
                                    const float* __restrict__ tbound,
                                    const float* __restrict__ w1p,
                                    const float* __restrict__ w2p,
                                    float* __restrict__ ws2,
                                    int S, int C, int swz) {
    __shared__ __align__(16) float ringA0[16 * 128];   // 16 planes x 4 steps x 32 t
    __shared__ __align__(16) float ringA1[16 * 128];
    __shared__ __align__(16) float ringB0[16 * 128];
    __shared__ __align__(16) float ringB1[16 * 128];
    __shared__ __align__(16) float ldsSA[TT];
    __shared__ __align__(16) float ldsSB[TT];
    int bs = (int)blockIdx.x;
    const int NB = C >> 1;
    if (swz) bs = (bs & 7) * (NB >> 3) + (bs >> 3);    // XCD-contiguous pairs
    const int lane = (int)threadIdx.x;
    const int t = lane & 31;
    const int h = lane >> 5;
    const int chA = 2 * bs;
    const int chB = 2 * bs + 1;
    const float w1 = w1p[0];
    const float w2 = w2p[0];
    const int Sm1 = S - 1;
    const int lane2 = lane * 2;
    const bool exact = (bs == 0);
    int s0A = exact ? 0 : (chA - 1) * 16;
    int s0B = (chB - 1) * 16;                          // == 0 when bs==0

    float trx[16];
#pragma unroll
    for (int i = 0; i < 16; ++i)
        trx[i] = __expf(w1 * trans[t * TT + h * 16 + i]);
    float trxsum = 0.0f;
#pragma unroll
    for (int i = 0; i < 16; ++i) trxsum += trx[i];

    float DA[16], DB[16];
#pragma unroll
    for (int k = 0; k < 16; ++k) {
        DA[k] = exact ? 0.0f : trxsum;
        DB[k] = exact ? 0.0f : trxsum;
    }
    if (!exact) { ldsSA[t] = 1.0f; ldsSB[t] = 1.0f; }  // ones init (H_{-1}=1)

    float etb0 = __expf(w1 * tbound[t]);
    float bem[16];
#pragma unroll
    for (int j = 0; j < 16; ++j) bem[j] = 0.0f;
    if (exact) {
#pragma unroll
        for (int j = 0; j < 16; ++j)                   // bemit[j] = feats[j][0][t]
            bem[j] = __expf(w2 * feats[(size_t)j * (size_t)S * 32u + (size_t)t]);
    }

    float mrefA = 0.0f, SvkA = 1.0f, invA = 1.0f;
    float mrefB = 0.0f, SvkB = 1.0f, invB = 1.0f;
    float2 gstA[16], gstB[16];                         // staged: next group

// issue 16 coalesced float2 loads for chain CH's 4-step group at offset OFF
#define LOADG(CH, OFF)                                                        \
    {                                                                         \
        int gs_ = s0##CH + (OFF); if (gs_ > S - 4) gs_ = S - 4;               \
        _Pragma("unroll")                                                     \
        for (int l = 0; l < 16; ++l)                                          \
            gst##CH[l] = *(const float2*)(feats +                             \
                ((size_t)l * (size_t)Sm1 + (size_t)gs_) * 32 + lane2);        \
    }

// write chain CH's staged regs into its ring buffer P, then load at OFF
#define GROUPOPS(CH, P, OFF)                                                  \
    {                                                                         \
        float* rw_ = (P) ? ring##CH##1 : ring##CH##0;                         \
        _Pragma("unroll")                                                     \
        for (int l = 0; l < 16; ++l)                                          \
            *(float2*)&rw_[l * 128 + lane2] = gst##CH[l];                     \
        LOADG(CH, OFF)                                                        \
    }

#define SCRF_STEP(CH, J, IS_B0, IS_FIRST, SCALED)                             \
    {                                                                         \
        const int j_ = (J);                                                   \
        const float* rb_ = ((j_ >> 2) & 1) ? ring##CH##1 : ring##CH##0;       \
        float ew_[16];                                                        \
        _Pragma("unroll")                                                     \
        for (int l = 0; l < 16; ++l)                                          \
            ew_[l] = __expf(w2 * rb_[l * 128 + (j_ & 3) * 32 + t]);           \
        float Dn_;                                                            \
        if (IS_FIRST) {                                                       \
            Dn_ = 0.0f;                                                       \
        } else {                                                              \
            const float4* lp_ = (const float4*)ldsS##CH;                      \
            float4 a0_ = lp_[h * 4 + 0];                                      \
            float4 a1_ = lp_[h * 4 + 1];                                      \
            float4 a2_ = lp_[h * 4 + 2];                                      \
            float4 a3_ = lp_[h * 4 + 3];                                      \
            float d0_ = fmaf(trx[0], a0_.x, fmaf(trx[1], a0_.y,               \
                        fmaf(trx[2], a0_.z, trx[3] * a0_.w)));                \
            float d1_ = fmaf(trx[4], a1_.x, fmaf(trx[5], a1_.y,               \
                        fmaf(trx[6], a1_.z, trx[7] * a1_.w)));                \
            float d2_ = fmaf(trx[8], a2_.x, fmaf(trx[9], a2_.y,               \
                        fmaf(trx[10], a2_.z, trx[11] * a2_.w)));              \
            float d3_ = fmaf(trx[12], a3_.x, fmaf(trx[13], a3_.y,             \
                        fmaf(trx[14], a3_.z, trx[15] * a3_.w)));              \
            float dh_ = (d0_ + d1_) + (d2_ + d3_);                            \
            Dn_ = (SCALED) ? dh_ * inv##CH : dh_;                             \
            D##CH[(j_ - 1) & 15] = Dn_;                                       \
        }                                                                     \
        float q0_ = D##CH[(j_ - 2) & 15] * ew_[1];                            \
        float q1_ = D##CH[(j_ - 3) & 15] * ew_[2];                            \
        float q2_ = D##CH[(j_ - 4) & 15] * ew_[3];                            \
        float q3_ = D##CH[(j_ - 5) & 15] * ew_[4];                            \
        q0_ = fmaf(D##CH[(j_ - 6) & 15], ew_[5], q0_);                        \
        q1_ = fmaf(D##CH[(j_ - 7) & 15], ew_[6], q1_);                        \
        q2_ = fmaf(D##CH[(j_ - 8) & 15], ew_[7], q2_);                        \
        q3_ = fmaf(D##CH[(j_ - 9) & 15], ew_[8], q3_);                        \
        q0_ = fmaf(D##CH[(j_ - 10) & 15], ew_[9], q0_);                       \
        q1_ = fmaf(D##CH[(j_ - 11) & 15], ew_[10], q1_);                      \
        q2_ = fmaf(D##CH[(j_ - 12) & 15], ew_[11], q2_);                      \
        q3_ = fmaf(D##CH[(j_ - 13) & 15], ew_[12], q3_);                      \
        q0_ = fmaf(D##CH[(j_ - 14) & 15], ew_[13], q0_);                      \
        q1_ = fmaf(D##CH[(j_ - 15) & 15], ew_[14], q1_);                      \
        q2_ = fmaf(D##CH[(j_ - 16) & 15], ew_[15], q2_);                      \
        float p15_ = (q0_ + q1_) + (q2_ + q3_);                               \
        p15_ = (t == 0) ? 0.0f : p15_;     /* O-tag: span len 1 only */       \
        float part_ = fmaf(Dn_, ew_[0], p15_);                                \
        float Sv_ = swap_sum(part_);                                          \
        if (IS_B0) {                                                          \
            float bt_ = etb0 * bem[j_];                                       \
            if (j_ > 0) bt_ = (t == 0) ? 0.0f : bt_;                          \
            Sv_ += bt_;                                                       \
        }                                                                     \
        ldsS##CH[t] = Sv_;                                                    \
        Svk##CH = Sv_;                                                        \
    }

// interleaved 16-step block for both chains (flags identical A/B by design)
#define BLOCK16_DUO(B0, FIRST, SCALED)                                        \
    SCRF_STEP(A, 0, B0, FIRST, SCALED) SCRF_STEP(B, 0, B0, FIRST, SCALED)     \
    SCRF_STEP(A, 1, B0, false, false)  SCRF_STEP(B, 1, B0, false, false)      \
    SCRF_STEP(A, 2, B0, false, false)  SCRF_STEP(B, 2, B0, false, false)      \
    SCRF_STEP(A, 3, B0, false, false)  SCRF_STEP(B, 3, B0, false, false)      \
    GROUPOPS(A, 1, 8)  GROUPOPS(B, 1, 8)                                      \
    SCRF_STEP(A, 4, B0, false, false)  SCRF_STEP(B, 4, B0, false, false)      \
    SCRF_STEP(A, 5, B0, false, false)  SCRF_STEP(B, 5, B0, false, false)      \
    SCRF_STEP(A, 6, B0, false, false)  SCRF_STEP(B, 6, B0, false, false)      \
    SCRF_STEP(A, 7, B0, false, false)  SCRF_STEP(B, 7, B0, false, false)      \
    GROUPOPS(A, 0, 12) GROUPOPS(B, 0, 12)                                     \
    SCRF_STEP(A, 8, B0, false, false)  SCRF_STEP(B, 8, B0, false, false)      \
    SCRF_STEP(A, 9, B0, false, false)  SCRF_STEP(B, 9, B0, false, false)      \
    SCRF_STEP(A, 10, B0, false, false) SCRF_STEP(B, 10, B0, false, false)     \
    SCRF_STEP(A, 11, B0, false, false) SCRF_STEP(B, 11, B0, false, false)     \
    GROUPOPS(A, 1, 16) GROUPOPS(B, 1, 16)                                     \
    SCRF_STEP(A, 12, B0, false, false) SCRF_STEP(B, 12, B0, false, false)     \
    SCRF_STEP(A, 13, B0, false, false) SCRF_STEP(B, 13, B0, false, false)     \
    SCRF_STEP(A, 14, B0, false, false) SCRF_STEP(B, 14, B0, false, false)     \
    SCRF_STEP(A, 15, B0, false, false) SCRF_STEP(B, 15, B0, false, false)     \
    GROUPOPS(A, 0, 20) GROUPOPS(B, 0, 20)

    // ---- prologue: group 0 -> ring0 (both chains), stage group 1 ----
    LOADG(A, 0)
    LOADG(B, 0)
    {
#pragma unroll
        for (int l = 0; l < 16; ++l) {
            *(float2*)&ringA0[l * 128 + lane2] = gstA[l];
            *(float2*)&ringB0[l * 128 + lane2] = gstB[l];
        }
    }
    LOADG(A, 4)
    LOADG(B, 4)

    // ---- block 0 (burn-in for bs>0; exact+boundary for bs==0) ----
    if (exact) {
        BLOCK16_DUO(true, true, false)
    } else {
        BLOCK16_DUO(false, false, false)
    }

    // ---- capture m at local step 15 (pre-rescale), both chains ----
    float svA = SvkA, svB = SvkB;
#pragma unroll
    for (int m = 1; m <= 16; m <<= 1) {
        svA += __shfl_xor(svA, m);
        svB += __shfl_xor(svB, m);
    }
    float m_preA = mrefA + __logf(svA);
    float m_preB = mrefB + __logf(svB);

    // ---- rescale both: D /= max_t(Sv), recenter to e^-20 ----
    float mxA = SvkA, mxB = SvkB;
#pragma unroll
    for (int m = 1; m <= 16; m <<= 1) {
        mxA = fmaxf(mxA, __shfl_xor(mxA, m));
        mxB = fmaxf(mxB, __shfl_xor(mxB, m));
    }
    invA = 2.0611536e-09f / mxA;   mrefA += __logf(mxA) + 20.0f;
    invB = 2.0611536e-09f / mxB;   mrefB += __logf(mxB) + 20.0f;
#pragma unroll
    for (int k = 0; k < 16; ++k) { DA[k] *= invA; DB[k] *= invB; }

    // ---- block 1 (payload) ----
    s0A += 16;
    s0B += 16;
    BLOCK16_DUO(false, false, true)
#undef BLOCK16_DUO
#undef SCRF_STEP
#undef GROUPOPS
#undef LOADG

    // ---- chunk outputs ----
    float seA = SvkA, seB = SvkB;
#pragma unroll
    for (int m = 1; m <= 16; m <<= 1) {
        seA += __shfl_xor(seA, m);
        seB += __shfl_xor(seB, m);
    }
    float m_endA = mrefA + __logf(seA);
    float m_endB = mrefB + __logf(seB);
    float contribA = (chA == 0) ? m_preA : (m_endA - m_preA);
    float contribB = m_endB - m_preB;
    if (lane == 0) {
        ws2[chA] = contribA;
        ws2[chB] = contribB;
    }
    if (chB == C - 1) {
        float etb1 = __expf(w1 * tbound[TT + t]);
        float sc = SvkB * etb1;
#pragma unroll
        for (int m = 1; m <= 16; m <<= 1) sc += __shfl_xor(sc, m);
        if (lane == 0) ws2[C] = __logf(sc) - __logf(seB);
    }
}

// ---------------------------------------------------------------------------
// Ordered reduction of the C+1 chunk contributions.
// ---------------------------------------------------------------------------
__global__ void stitch_kernel(const float* __restrict__ ws2,
                              float* __restrict__ out, int n) {
    const int lane = (int)threadIdx.x;
    float v = 0.0f;
    for (int i = lane; i < n; i += 64) v += ws2[i];
#pragma unroll
    for (int m = 1; m <= 32; m <<= 1) v += __shfl_xor(v, m);
    if (lane == 0) out[0] = v;
}

// ---------------------------------------------------------------------------
// Fallback (S not a multiple of 32 / tiny ws): proven round-2 kernel.
// ---------------------------------------------------------------------------
__launch_bounds__(64, 1)
__global__ void semicrf_scan_fb_kernel(const float* __restrict__ src,
                                       const float* __restrict__ trans,
                                       const float* __restrict__ tbound,
                                       const float* __restrict__ w1p,
                                       const float* __restrict__ w2p,
                                       float* __restrict__ out, int S) {
    __shared__ float4 ldsS4[8];
    const int lane = threadIdx.x;
    const int t = lane & 31;
    const int h = lane >> 5;
    const float w1 = w1p[0];
    const float w2 = w2p[0];
    const unsigned toff = (unsigned)t * 4u;
    const unsigned planeB = (unsigned)S * 128u;
    const size_t planeE = (size_t)S * TT;

    float trx[16];
#pragma unroll
    for (int i = 0; i < 16; ++i)
        trx[i] = __expf(w1 * trans[t * TT + h * 16 + i]);

    float D[16];
#pragma unroll
    for (int k = 0; k < 16; ++k) D[k] = 0.0f;

    unsigned off[16];
#pragma unroll
    for (int k = 0; k < 16; ++k) {
        int l = (-1 - k) & 15;
        int c = 0 - l; if (c < 0) c = 0;
        off[k] = (unsigned)(l * S + c) * 128u + toff;
    }

    float ring[4][16];
#pragma unroll
    for (int st = 0; st < 4; ++st) {
#pragma unroll
        for (int k = 0; k < 16; ++k)
            ring[st][k] = *(const float*)((const char*)src + off[k]);
        const int qr = st & 15;
        unsigned c = (unsigned)((st + 1 <= S - 1) ? st + 1 : S - 1);
#pragma unroll
        for (int k = 0; k < 16; ++k)
            off[k] = (k == qr) ? (c * 128u + toff) : (off[k] + planeB);
    }

    float etb0 = __expf(w1 * tbound[t]);
    float bem[16];
#pragma unroll
    for (int j = 0; j < 16; ++j)
        bem[j] = __expf(w2 * src[(size_t)j * planeE + (size_t)t]);

    float mref = 0.0f;
    float Svk = 1.0f;

#define FB_STEP(J, S0V, IS_B0)                                                \
    {                                                                         \
        const int j_ = (J);                                                   \
        float ewv[16];                                                        \
        _Pragma("unroll")                                                     \
        for (int k = 0; k < 16; ++k)                                          \
            ewv[k] = __expf(w2 * ring[j_ & 3][k]);                            \
        float p0 = 0.f, p1 = 0.f, p2 = 0.f, p3 = 0.f;                         \
        _Pragma("unroll")                                                     \
        for (int k = 0; k < 16; k += 4) {                                     \
            p0 = fmaf(D[k + 0], ewv[k + 0], p0);                              \
            p1 = fmaf(D[k + 1], ewv[k + 1], p1);                              \
            p2 = fmaf(D[k + 2], ewv[k + 2], p2);                              \
            p3 = fmaf(D[k + 3], ewv[k + 3], p3);                              \
        }                                                                     \
        float part = (p0 + p1) + (p2 + p3);                                   \
        {                                                                     \
            const int kp = (j_ - 1) & 15;                                     \
            float alt = D[kp] * ewv[kp];                                      \
            part = (t == 0) ? alt : part;                                     \
        }                                                                     \
        _Pragma("unroll")                                                     \
        for (int k = 0; k < 16; ++k)                                          \
            ring[(j_ + 4) & 3][k] =                                           \
                *(const float*)((const char*)src + off[k]);                   \
        {                                                                     \
            const int qr = (j_ + 4) & 15;                                     \
            long T1 = (long)(S0V) + j_ + 4 + 1;                               \
            unsigned c_ = (unsigned)(T1 <= (long)(S - 1) ? T1 : (long)(S - 1)); \
            _Pragma("unroll")                                                 \
            for (int k = 0; k < 16; ++k)                                      \
                off[k] = (k == qr) ? (c_ * 128u + toff) : (off[k] + planeB);  \
        }                                                                     \
        float Sv = part + __shfl_xor(part, 32);                               \
        if (IS_B0) {                                                          \
            float bt = etb0 * bem[j_];                                        \
            if (j_ > 0) bt = (t == 0) ? 0.0f : bt;                            \
            Sv += bt;                                                         \
        }                                                                     \
        ((float*)ldsS4)[t] = Sv;                                              \
        __syncthreads();                                                      \
        float4 a0 = ldsS4[h * 4 + 0];                                         \
        float4 a1 = ldsS4[h * 4 + 1];                                         \
        float4 a2 = ldsS4[h * 4 + 2];                                         \
        float4 a3 = ldsS4[h * 4 + 3];                                         \
        float dn0 = fmaf(trx[0],  a0.x, fmaf(trx[1],  a0.y,                   \
                    fmaf(trx[2],  a0.z, trx[3]  * a0.w)));                    \
        float dn1 = fmaf(trx[4],  a1.x, fmaf(trx[5],  a1.y,                   \
                    fmaf(trx[6],  a1.z, trx[7]  * a1.w)));                    \
        float dn2 = fmaf(trx[8],  a2.x, fmaf(trx[9],  a2.y,                   \
                    fmaf(trx[10], a2.z, trx[11] * a2.w)));                    \
        float dn3 = fmaf(trx[12], a3.x, fmaf(trx[13], a3.y,                   \
                    fmaf(trx[14], a3.z, trx[15] * a3.w)));                    \
        D[j_] = (dn0 + dn1) + (dn2 + dn3);                                    \
        Svk = Sv;                                                             \
    }

#pragma unroll
    for (int j = 0; j < 16; ++j) {
        FB_STEP(j, 0L, true)
    }
    const int nblocks = S / 16;
    long s0 = 16;
    for (int b = 1; b < nblocks; ++b) {
        float mx = Svk;
#pragma unroll
        for (int m = 1; m <= 16; m <<= 1)
            mx = fmaxf(mx, __shfl_xor(mx, m));
        float invv = 2.0611536e-09f / mx;
        mref += __logf(mx) + 20.0f;
#pragma unroll
        for (int k = 0; k < 16; ++k) D[k] *= invv;
#pragma unroll
        for (int j = 0; j < 16; ++j) {
            FB_STEP(j, s0, false)
        }
        s0 += 16;
    }
#undef FB_STEP

    float etb1 = __expf(w1 * tbound[TT + t]);
    float val = Svk * etb1;
#pragma unroll
    for (int m = 1; m <= 16; m <<= 1) val += __shfl_xor(val, m);
    if (lane == 0) out[0] = mref + __logf(val);
}

// ---------------------------------------------------------------------------
extern "C" void kernel_launch(void* const* d_in, const int* in_sizes, int n_in,
                              void* d_out, int out_size, void* d_ws, size_t ws_size,
                              hipStream_t stream) {
    const float* feats = (const float*)d_in[0];   // [L=16, S, T=32]
    const float* trans = (const float*)d_in[1];   // [T, T]
    const float* tb    = (const float*)d_in[2];   // [2, T]
    const float* w1    = (const float*)d_in[3];
    const float* w2    = (const float*)d_in[4];
    float* out = (float*)d_out;

    const int n = in_sizes[0];            // L*S*T
    const int S = n / (LL * TT);

    // K=16 chunks, two per wave (ILP-interleaved): need S % 32 == 0.
    int C = 0;
    if ((S & 31) == 0 && S >= 64) C = S >> 4;
    const int NB = C >> 1;
    const int swz = (NB > 0 && (NB & 7) == 0) ? 1 : 0;

    const size_t need = (size_t)(C + 2) * sizeof(float);
    if (C > 1 && ws_size >= need) {
        float* ws2 = (float*)d_ws;
        semicrf_duo2_kernel<<<NB, 64, 0, stream>>>(feats, trans, tb, w1, w2,
                                                   ws2, S, C, swz);
        stitch_kernel<<<1, 64, 0, stream>>>(ws2, out, C + 1);
    } else {
        semicrf_scan_fb_kernel<<<1, 64, 0, stream>>>(feats, trans, tb, w1, w2, out, S);
    }
}

// Round 14
// 32.274 us; speedup vs baseline: 2.8858x; 1.5041x over previous
//
#include <hip/hip_runtime.h>

#define TT 32     // tags
#define LL 16     // max span length
#define BURN 16   // burn-in steps (validated r11: absmax 0.0)
#define KCH 32    // chunk payload length (steps)

// broadcast lane p's value to all lanes (VALU/SALU readlane, no LDS pipe)
#if __has_builtin(__builtin_amdgcn_readlane)
#define RLF(U, P) __uint_as_float(__builtin_amdgcn_readlane((U), (P)))
#else
#define RLF(U, P) __uint_as_float(__shfl((int)(U), (P)))
#endif

// ---------------------------------------------------------------------------
// Chunk-parallel scan, readlane-MVM edition.
// Chunk c covers payload [c*32,(c+1)*32); gstart = max(0, c*32-16); c>0 burns
// in 16 steps from an all-ones state (projective contraction; absmax 0.0
// validated at BURN=16). Per lane: tag t = lane&31 (halves duplicate), FULL
// 32-wide Trx row; after the dot every lane holds the complete S_t, so the
// next step's MVM uses 32x v_readlane broadcasts + 32 fma -- zero LDS on the
// recurrence. Emissions: 8-step groups staged float4/lane (1KB contiguous
// per plane), exp applied at stage time, double-buffered 16KB rings.
// Each chunk reports m_end - m_pre of m(x)=log(sum_t H[t]); chunk whose
// window starts at 0 reports absolute m_end; last chunk adds the terminal
// correction; ws2 telescopes.
// ---------------------------------------------------------------------------
__launch_bounds__(64, 1)
__global__ void semicrf_rl_kernel(const float* __restrict__ feats,
                                  const float* __restrict__ trans,
                                  const float* __restrict__ tbound,
                                  const float* __restrict__ w1p,
                                  const float* __restrict__ w2p,
                                  float* __restrict__ ws2,
                                  int S, int C, int swz) {
    __shared__ __align__(16) float ring0[16 * 256];  // 16 planes x 8 steps x 32 t
    __shared__ __align__(16) float ring1[16 * 256];
    int c = (int)blockIdx.x;
    if (swz) c = (c & 7) * (C >> 3) + (c >> 3);      // XCD-contiguous chunks
    const int lane = (int)threadIdx.x;
    const int t = lane & 31;
    const float w1 = w1p[0];
    const float w2 = w2p[0];
    const int Sm1 = S - 1;

    int gstart = c * KCH - BURN;
    if (gstart < 0) gstart = 0;
    const bool exact = (gstart == 0);
    const int nb = ((c + 1) * KCH - gstart) >> 4;    // 16-step blocks
    const int preb = (c * KCH - gstart) >> 4;        // m_pre capture block

    // full Trx row for this lane's tag (32 regs)
    float trx[32];
#pragma unroll
    for (int i = 0; i < 32; ++i)
        trx[i] = __expf(w1 * trans[t * TT + i]);
    float trxsum = 0.0f;
#pragma unroll
    for (int i = 0; i < 32; ++i) trxsum += trx[i];

    float D[16];
#pragma unroll
    for (int k = 0; k < 16; ++k) D[k] = exact ? 0.0f : trxsum;

    float etb0 = __expf(w1 * tbound[t]);
    float bem[16];
#pragma unroll
    for (int j = 0; j < 16; ++j) bem[j] = 0.0f;
    if (exact) {
#pragma unroll
        for (int j = 0; j < 16; ++j)                 // bemit[j] = feats[j][0][t]
            bem[j] = __expf(w2 * feats[(size_t)j * (size_t)S * 32u + (size_t)t]);
    }

    float mref = 0.0f, Svk = 1.0f, inv = 1.0f;
    float Svp = 1.0f;                                // prev step's full S_t (ones init)
    int s0 = gstart;
    float4 gst[16];                                  // staged raw: next 8 steps

// issue 16 float4 loads: 8-step strip (1KB contiguous) per plane at s0+OFF
#define LOADG(OFF)                                                            \
    {                                                                         \
        int gs_ = s0 + (OFF); if (gs_ > S - 8) gs_ = S - 8;                   \
        _Pragma("unroll")                                                     \
        for (int l = 0; l < 16; ++l)                                          \
            gst[l] = *(const float4*)(feats +                                 \
                ((size_t)l * (size_t)Sm1 + (size_t)gs_) * 32 + lane * 4);     \
    }

// exp the staged regs and write to ring buffer P, then load s0+OFF
#define GROUPOPS(P, OFF)                                                      \
    {                                                                         \
        float* rw_ = (P) ? ring1 : ring0;                                     \
        _Pragma("unroll")                                                     \
        for (int l = 0; l < 16; ++l) {                                        \
            float4 e_;                                                        \
            e_.x = __expf(w2 * gst[l].x);                                     \
            e_.y = __expf(w2 * gst[l].y);                                     \
            e_.z = __expf(w2 * gst[l].z);                                     \
            e_.w = __expf(w2 * gst[l].w);                                     \
            *(float4*)&rw_[l * 256 + lane * 4] = e_;                          \
        }                                                                     \
        LOADG(OFF)                                                            \
    }

#define SCRF_STEP(J, IS_B0, IS_FIRST, SCALED)                                 \
    {                                                                         \
        const int j_ = (J);                                                   \
        const float* rb_ = (j_ >= 8) ? ring1 : ring0;                         \
        /* 16 pre-exp'd emissions (bank = t, broadcast across halves) */      \
        float ew_[16];                                                        \
        _Pragma("unroll")                                                     \
        for (int l = 0; l < 16; ++l)                                          \
            ew_[l] = rb_[l * 256 + (j_ & 7) * 32 + t];                        \
        /* MVM via 32x readlane of prev S (no LDS on the chain) */            \
        float Dn_;                                                            \
        if (IS_FIRST) {                                                       \
            Dn_ = 0.0f;                                                       \
        } else {                                                              \
            unsigned svu_ = __float_as_uint(Svp);                             \
            float ac_[4] = {0.f, 0.f, 0.f, 0.f};                              \
            _Pragma("unroll")                                                 \
            for (int p = 0; p < 32; ++p)                                      \
                ac_[p & 3] = fmaf(trx[p], RLF(svu_, p), ac_[p & 3]);          \
            float dh_ = (ac_[0] + ac_[1]) + (ac_[2] + ac_[3]);                \
            Dn_ = (SCALED) ? dh_ * inv : dh_;                                 \
            D[(j_ - 1) & 15] = Dn_;                                           \
        }                                                                     \
        float q0_ = D[(j_ - 2) & 15] * ew_[1];                                \
        float q1_ = D[(j_ - 3) & 15] * ew_[2];                                \
        float q2_ = D[(j_ - 4) & 15] * ew_[3];                                \
        float q3_ = D[(j_ - 5) & 15] * ew_[4];                                \
        q0_ = fmaf(D[(j_ - 6) & 15], ew_[5], q0_);                            \
        q1_ = fmaf(D[(j_ - 7) & 15], ew_[6], q1_);                            \
        q2_ = fmaf(D[(j_ - 8) & 15], ew_[7], q2_);                            \
        q3_ = fmaf(D[(j_ - 9) & 15], ew_[8], q3_);                            \
        q0_ = fmaf(D[(j_ - 10) & 15], ew_[9], q0_);                           \
        q1_ = fmaf(D[(j_ - 11) & 15], ew_[10], q1_);                          \
        q2_ = fmaf(D[(j_ - 12) & 15], ew_[11], q2_);                          \
        q3_ = fmaf(D[(j_ - 13) & 15], ew_[12], q3_);                          \
        q0_ = fmaf(D[(j_ - 14) & 15], ew_[13], q0_);                          \
        q1_ = fmaf(D[(j_ - 15) & 15], ew_[14], q1_);                          \
        q2_ = fmaf(D[(j_ - 16) & 15], ew_[15], q2_);                          \
        float p15_ = (q0_ + q1_) + (q2_ + q3_);                               \
        p15_ = (t == 0) ? 0.0f : p15_;     /* O-tag: span len 1 only */       \
        float Sv_ = fmaf(Dn_, ew_[0], p15_);                                  \
        if (IS_B0) {                                                          \
            float bt_ = etb0 * bem[j_];                                       \
            if (j_ > 0) bt_ = (t == 0) ? 0.0f : bt_;                          \
            Sv_ += bt_;                                                       \
        }                                                                     \
        Svp = Sv_;                                                            \
        Svk = Sv_;                                                            \
    }

// one 16-step block = 2 groups of 8. Invariant on entry: ring0 = s0..s0+7,
// gst = s0+8..s0+15 (raw). Exit: same with s0' = s0+16.
#define BLOCK16(B0, FIRST, SCALED)                                            \
    SCRF_STEP(0, B0, FIRST, SCALED)                                           \
    SCRF_STEP(1, B0, false, false)                                            \
    SCRF_STEP(2, B0, false, false)                                            \
    SCRF_STEP(3, B0, false, false)                                            \
    SCRF_STEP(4, B0, false, false)                                            \
    SCRF_STEP(5, B0, false, false)                                            \
    SCRF_STEP(6, B0, false, false)                                            \
    SCRF_STEP(7, B0, false, false)                                            \
    GROUPOPS(1, 16)                                                           \
    SCRF_STEP(8, B0, false, false)                                            \
    SCRF_STEP(9, B0, false, false)                                            \
    SCRF_STEP(10, B0, false, false)                                           \
    SCRF_STEP(11, B0, false, false)                                           \
    SCRF_STEP(12, B0, false, false)                                           \
    SCRF_STEP(13, B0, false, false)                                           \
    SCRF_STEP(14, B0, false, false)                                           \
    SCRF_STEP(15, B0, false, false)                                           \
    GROUPOPS(0, 24)

    // ---- prologue: steps s0..s0+7 -> ring0 (exp'd), stage s0+8..15 ----
    LOADG(0)
    {
#pragma unroll
        for (int l = 0; l < 16; ++l) {
            float4 e_;
            e_.x = __expf(w2 * gst[l].x);
            e_.y = __expf(w2 * gst[l].y);
            e_.z = __expf(w2 * gst[l].z);
            e_.w = __expf(w2 * gst[l].w);
            *(float4*)&ring0[l * 256 + lane * 4] = e_;
        }
    }
    LOADG(8)

    // ---- block 0 ----
    if (exact) {
        BLOCK16(true, true, false)
    } else {
        BLOCK16(false, false, false)
    }

    // ---- remaining blocks ----
    float m_pre = 0.0f;
    for (int b = 1; b < nb; ++b) {
        s0 += 16;
        if (b == preb) {   // capture m at global step c*K-1 (pre-rescale)
            float sv = Svk;
#pragma unroll
            for (int m = 1; m <= 16; m <<= 1) sv += __shfl_xor(sv, m);
            m_pre = mref + __logf(sv);
        }
        // re-anchor: divide history by max_t(Sv_last), recenter to e^-20
        float mx = Svk;
#pragma unroll
        for (int m = 1; m <= 16; m <<= 1)
            mx = fmaxf(mx, __shfl_xor(mx, m));
        inv = 2.0611536e-09f / mx;          // e^-20 / mx
        mref += __logf(mx) + 20.0f;
#pragma unroll
        for (int k = 0; k < 16; ++k) D[k] *= inv;

        BLOCK16(false, false, true)         // pending Svp's MVM gets *inv
    }
#undef BLOCK16
#undef SCRF_STEP
#undef GROUPOPS
#undef LOADG

    // ---- chunk outputs ----
    float se = Svk;
#pragma unroll
    for (int m = 1; m <= 16; m <<= 1) se += __shfl_xor(se, m);
    float m_end = mref + __logf(se);
    float contrib = (preb == 0) ? m_end : (m_end - m_pre);
    if (lane == 0) ws2[c] = contrib;
    if (c == C - 1) {
        float etb1 = __expf(w1 * tbound[TT + t]);
        float sc = Svk * etb1;
#pragma unroll
        for (int m = 1; m <= 16; m <<= 1) sc += __shfl_xor(sc, m);
        if (lane == 0) ws2[C] = __logf(sc) - __logf(se);
    }
}

// ---------------------------------------------------------------------------
// Ordered reduction of the C+1 chunk contributions.
// ---------------------------------------------------------------------------
__global__ void stitch_kernel(const float* __restrict__ ws2,
                              float* __restrict__ out, int n) {
    const int lane = (int)threadIdx.x;
    float v = 0.0f;
    for (int i = lane; i < n; i += 64) v += ws2[i];
#pragma unroll
    for (int m = 1; m <= 32; m <<= 1) v += __shfl_xor(v, m);
    if (lane == 0) out[0] = v;
}

// ---------------------------------------------------------------------------
// Fallback (S not a multiple of 32 / tiny ws): proven round-2 kernel.
// ---------------------------------------------------------------------------
__launch_bounds__(64, 1)
__global__ void semicrf_scan_fb_kernel(const float* __restrict__ src,
                                       const float* __restrict__ trans,
                                       const float* __restrict__ tbound,
                                       const float* __restrict__ w1p,
                                       const float* __restrict__ w2p,
                                       float* __restrict__ out, int S) {
    __shared__ float4 ldsS4[8];
    const int lane = threadIdx.x;
    const int t = lane & 31;
    const int h = lane >> 5;
    const float w1 = w1p[0];
    const float w2 = w2p[0];
    const unsigned toff = (unsigned)t * 4u;
    const unsigned planeB = (unsigned)S * 128u;
    const size_t planeE = (size_t)S * TT;

    float trx[16];
#pragma unroll
    for (int i = 0; i < 16; ++i)
        trx[i] = __expf(w1 * trans[t * TT + h * 16 + i]);

    float D[16];
#pragma unroll
    for (int k = 0; k < 16; ++k) D[k] = 0.0f;

    unsigned off[16];
#pragma unroll
    for (int k = 0; k < 16; ++k) {
        int l = (-1 - k) & 15;
        int c = 0 - l; if (c < 0) c = 0;
        off[k] = (unsigned)(l * S + c) * 128u + toff;
    }

    float ring[4][16];
#pragma unroll
    for (int st = 0; st < 4; ++st) {
#pragma unroll
        for (int k = 0; k < 16; ++k)
            ring[st][k] = *(const float*)((const char*)src + off[k]);
        const int qr = st & 15;
        unsigned c = (unsigned)((st + 1 <= S - 1) ? st + 1 : S - 1);
#pragma unroll
        for (int k = 0; k < 16; ++k)
            off[k] = (k == qr) ? (c * 128u + toff) : (off[k] + planeB);
    }

    float etb0 = __expf(w1 * tbound[t]);
    float bem[16];
#pragma unroll
    for (int j = 0; j < 16; ++j)
        bem[j] = __expf(w2 * src[(size_t)j * planeE + (size_t)t]);

    float mref = 0.0f;
    float Svk = 1.0f;

#define FB_STEP(J, S0V, IS_B0)                                                \
    {                                                                         \
        const int j_ = (J);                                                   \
        float ewv[16];                                                        \
        _Pragma("unroll")                                                     \
        for (int k = 0; k < 16; ++k)                                          \
            ewv[k] = __expf(w2 * ring[j_ & 3][k]);                            \
        float p0 = 0.f, p1 = 0.f, p2 = 0.f, p3 = 0.f;                         \
        _Pragma("unroll")                                                     \
        for (int k = 0; k < 16; k += 4) {                                     \
            p0 = fmaf(D[k + 0], ewv[k + 0], p0);                              \
            p1 = fmaf(D[k + 1], ewv[k + 1], p1);                              \
            p2 = fmaf(D[k + 2], ewv[k + 2], p2);                              \
            p3 = fmaf(D[k + 3], ewv[k + 3], p3);                              \
        }                                                                     \
        float part = (p0 + p1) + (p2 + p3);                                   \
        {                                                                     \
            const int kp = (j_ - 1) & 15;                                     \
            float alt = D[kp] * ewv[kp];                                      \
            part = (t == 0) ? alt : part;                                     \
        }                                                                     \
        _Pragma("unroll")                                                     \
        for (int k = 0; k < 16; ++k)                                          \
            ring[(j_ + 4) & 3][k] =                                           \
                *(const float*)((const char*)src + off[k]);                   \
        {                                                                     \
            const int qr = (j_ + 4) & 15;                                     \
            long T1 = (long)(S0V) + j_ + 4 + 1;                               \
            unsigned c_ = (unsigned)(T1 <= (long)(S - 1) ? T1 : (long)(S - 1)); \
            _Pragma("unroll")                                                 \
            for (int k = 0; k < 16; ++k)                                      \
                off[k] = (k == qr) ? (c_ * 128u + toff) : (off[k] + planeB);  \
        }                                                                     \
        float Sv = part + __shfl_xor(part, 32);                               \
        if (IS_B0) {                                                          \
            float bt = etb0 * bem[j_];                                        \
            if (j_ > 0) bt = (t == 0) ? 0.0f : bt;                            \
            Sv += bt;                                                         \
        }                                                                     \
        ((float*)ldsS4)[t] = Sv;                                              \
        __syncthreads();                                                      \
        float4 a0 = ldsS4[h * 4 + 0];                                         \
        float4 a1 = ldsS4[h * 4 + 1];                                         \
        float4 a2 = ldsS4[h * 4 + 2];                                         \
        float4 a3 = ldsS4[h * 4 + 3];                                         \
        float dn0 = fmaf(trx[0],  a0.x, fmaf(trx[1],  a0.y,                   \
                    fmaf(trx[2],  a0.z, trx[3]  * a0.w)));                    \
        float dn1 = fmaf(trx[4],  a1.x, fmaf(trx[5],  a1.y,                   \
                    fmaf(trx[6],  a1.z, trx[7]  * a1.w)));                    \
        float dn2 = fmaf(trx[8],  a2.x, fmaf(trx[9],  a2.y,                   \
                    fmaf(trx[10], a2.z, trx[11] * a2.w)));                    \
        float dn3 = fmaf(trx[12], a3.x, fmaf(trx[13], a3.y,                   \
                    fmaf(trx[14], a3.z, trx[15] * a3.w)));                    \
        D[j_] = (dn0 + dn1) + (dn2 + dn3);                                    \
        Svk = Sv;                                                             \
    }

#pragma unroll
    for (int j = 0; j < 16; ++j) {
        FB_STEP(j, 0L, true)
    }
    const int nblocks = S / 16;
    long s0 = 16;
    for (int b = 1; b < nblocks; ++b) {
        float mx = Svk;
#pragma unroll
        for (int m = 1; m <= 16; m <<= 1)
            mx = fmaxf(mx, __shfl_xor(mx, m));
        float invv = 2.0611536e-09f / mx;
        mref += __logf(mx) + 20.0f;
#pragma unroll
        for (int k = 0; k < 16; ++k) D[k] *= invv;
#pragma unroll
        for (int j = 0; j < 16; ++j) {
            FB_STEP(j, s0, false)
        }
        s0 += 16;
    }
#undef FB_STEP

    float etb1 = __expf(w1 * tbound[TT + t]);
    float val = Svk * etb1;
#pragma unroll
    for (int m = 1; m <= 16; m <<= 1) val += __shfl_xor(val, m);
    if (lane == 0) out[0] = mref + __logf(val);
}

// ---------------------------------------------------------------------------
extern "C" void kernel_launch(void* const* d_in, const int* in_sizes, int n_in,
                              void* d_out, int out_size, void* d_ws, size_t ws_size,
                              hipStream_t stream) {
    const float* feats = (const float*)d_in[0];   // [L=16, S, T=32]
    const float* trans = (const float*)d_in[1];   // [T, T]
    const float* tb    = (const float*)d_in[2];   // [2, T]
    const float* w1    = (const float*)d_in[3];
    const float* w2    = (const float*)d_in[4];
    float* out = (float*)d_out;

    const int n = in_sizes[0];            // L*S*T
    const int S = n / (LL * TT);

    // K=32 chunks (BURN=16): need S % 32 == 0.
    int C = 0;
    if ((S & 31) == 0 && S >= 96) C = S >> 5;
    const int swz = (C > 0 && (C & 7) == 0) ? 1 : 0;

    const size_t need = (size_t)(C + 2) * sizeof(float);
    if (C > 1 && ws_size >= need) {
        float* ws2 = (float*)d_ws;
        semicrf_rl_kernel<<<C, 64, 0, stream>>>(feats, trans, tb, w1, w2,
                                                ws2, S, C, swz);
        stitch_kernel<<<1, 64, 0, stream>>>(ws2, out, C + 1);
    } else {
        semicrf_scan_fb_kernel<<<1, 64, 0, stream>>>(feats, trans, tb, w1, w2, out, S);
    }
}